// Round 1
// baseline (269.233 us; speedup 1.0000x reference)
//
#include <hip/hip_runtime.h>
#include <stdint.h>

// Post-processor: per-class score threshold + stable sort + greedy NMS + global top-100.
// N=2048 proposals, C=81 classes (class 0 = background, dropped).
// Inputs:  d_in[0] = boxes  [2048, 324] f32  (N x C*4, xyxy per (proposal,class))
//          d_in[1] = scores [2048, 81]  f32
// Output:  d_out = [100, 6] f32  (x1,y1,x2,y2,score,label)
// Workspace: 80*100*6 floats = 192000 bytes of d_ws.

#define NPROP   2048
#define NCLS    81
#define SCORE_T 0.05f
#define NMS_T   0.5f
#define PERCLS  100
#define NREC    (80 * PERCLS)   // 8000
#define PADK    8192
#define NEGINF  -1.0e9f

// Order-preserving float->uint mapping (ascending floats -> ascending uints).
__device__ __forceinline__ unsigned fflip(float f) {
  unsigned u = __float_as_uint(f);
  return (u & 0x80000000u) ? ~u : (u | 0x80000000u);
}
__device__ __forceinline__ float funflip(unsigned u) {
  unsigned v = (u & 0x80000000u) ? (u ^ 0x80000000u) : ~u;
  return __uint_as_float(v);
}

// One block per foreground class. Sort candidates by (score desc, idx asc),
// greedy NMS among valid candidates only, write up to 100 kept records.
__global__ __launch_bounds__(256) void nms_per_class_kernel(
    const float* __restrict__ boxes, const float* __restrict__ scores,
    float* __restrict__ rec) {
  __shared__ unsigned long long keys[NPROP];   // 16 KB
  __shared__ float bx[NPROP][4];               // 32 KB
  __shared__ int   keep[NPROP];                //  8 KB
  __shared__ int   mcount;
  const int tid = threadIdx.x;
  const int c = blockIdx.x + 1;                // class 1..80

  if (tid == 0) mcount = 0;
  __syncthreads();

  // Load scores for this class; key = (flip(score) << 32) | (~idx)
  // so descending key order == (score desc, proposal idx asc) — matches
  // the reference's stable argsort(-s_masked).
  int localcnt = 0;
  for (int i = tid; i < NPROP; i += 256) {
    float s = scores[i * NCLS + c];
    float ks;
    if (s > SCORE_T) { ks = s; localcnt++; } else { ks = -3.0e38f; }
    keys[i] = ((unsigned long long)fflip(ks) << 32) |
              (unsigned)(0xFFFFFFFFu - (unsigned)i);
  }
  if (localcnt) atomicAdd(&mcount, localcnt);

  // Bitonic sort, descending, P = 2048 (keys unique -> deterministic).
  for (int k = 2; k <= NPROP; k <<= 1) {
    for (int j = k >> 1; j > 0; j >>= 1) {
      __syncthreads();
      for (int i = tid; i < NPROP; i += 256) {
        int ixj = i ^ j;
        if (ixj > i) {
          unsigned long long a = keys[i], b = keys[ixj];
          if (((i & k) == 0) ? (a < b) : (a > b)) { keys[i] = b; keys[ixj] = a; }
        }
      }
    }
  }
  __syncthreads();
  const int M = mcount;   // number of valid candidates (score > thresh)

  // Gather + clip candidate boxes (same clip as reference: remove_empty=False).
  for (int r = tid; r < M; r += 256) {
    unsigned pi = 0xFFFFFFFFu - (unsigned)(keys[r] & 0xFFFFFFFFull);
    const float* bp = boxes + (size_t)pi * (NCLS * 4) + c * 4;
    bx[r][0] = fminf(fmaxf(bp[0], 0.f), 1332.f);
    bx[r][1] = fminf(fmaxf(bp[1], 0.f), 799.f);
    bx[r][2] = fminf(fmaxf(bp[2], 0.f), 1332.f);
    bx[r][3] = fminf(fmaxf(bp[3], 0.f), 799.f);
    keep[r] = 1;
  }
  __syncthreads();

  // Greedy NMS: iteration i suppresses j > i only, so keep[i] is stable when
  // read; all threads read the same value; writes to distinct j per thread.
  for (int i = 0; i < M; ++i) {
    if (keep[i]) {
      const float ax1 = bx[i][0], ay1 = bx[i][1], ax2 = bx[i][2], ay2 = bx[i][3];
      const float aarea = fmaxf(ax2 - ax1, 0.f) * fmaxf(ay2 - ay1, 0.f);
      for (int j = i + 1 + tid; j < M; j += 256) {
        if (keep[j]) {
          float ix1 = fmaxf(ax1, bx[j][0]);
          float iy1 = fmaxf(ay1, bx[j][1]);
          float ix2 = fminf(ax2, bx[j][2]);
          float iy2 = fminf(ay2, bx[j][3]);
          float inter = fmaxf(ix2 - ix1, 0.f) * fmaxf(iy2 - iy1, 0.f);
          float barea = fmaxf(bx[j][2] - bx[j][0], 0.f) *
                        fmaxf(bx[j][3] - bx[j][1], 0.f);
          float iou = inter / (aarea + barea - inter + 1e-9f);
          if (iou > NMS_T) keep[j] = 0;
        }
      }
    }
    __syncthreads();
  }

  // Emit up to 100 kept records in score order; pad rest with NEG_INF score.
  // (Global top-100 can take at most 100 from one class, so 100/class suffices.)
  if (tid == 0) {
    float* base = rec + (size_t)(c - 1) * PERCLS * 6;
    int kk = 0;
    for (int r = 0; r < M && kk < PERCLS; ++r) {
      if (keep[r]) {
        float s = funflip((unsigned)(keys[r] >> 32));
        float* o = base + kk * 6;
        o[0] = bx[r][0]; o[1] = bx[r][1]; o[2] = bx[r][2]; o[3] = bx[r][3];
        o[4] = s; o[5] = (float)c;
        ++kk;
      }
    }
    for (; kk < PERCLS; ++kk) {
      float* o = base + kk * 6;
      o[0] = 0.f; o[1] = 0.f; o[2] = 0.f; o[3] = 0.f; o[4] = NEGINF; o[5] = 0.f;
    }
  }
}

// Single block: global top-100 over the 8000 per-class records.
// Tie order (equal scores): smaller entry index first == smaller class /
// earlier sorted rank — consistent with lax.top_k's lowest-flat-index rule.
__global__ __launch_bounds__(1024) void topk_kernel(
    const float* __restrict__ rec, float* __restrict__ out) {
  __shared__ unsigned long long keys[PADK];    // 64 KB
  const int tid = threadIdx.x;
  for (int e = tid; e < PADK; e += 1024) {
    float s = (e < NREC) ? rec[(size_t)e * 6 + 4] : -3.0e38f;
    keys[e] = ((unsigned long long)fflip(s) << 32) |
              (unsigned)(0xFFFFFFFFu - (unsigned)e);
  }
  for (int k = 2; k <= PADK; k <<= 1) {
    for (int j = k >> 1; j > 0; j >>= 1) {
      __syncthreads();
      for (int i = tid; i < PADK; i += 1024) {
        int ixj = i ^ j;
        if (ixj > i) {
          unsigned long long a = keys[i], b = keys[ixj];
          if (((i & k) == 0) ? (a < b) : (a > b)) { keys[i] = b; keys[ixj] = a; }
        }
      }
    }
  }
  __syncthreads();
  if (tid < 100) {
    unsigned e = 0xFFFFFFFFu - (unsigned)(keys[tid] & 0xFFFFFFFFull);
    float* o = out + tid * 6;
    if (e < NREC) {
      const float* r = rec + (size_t)e * 6;
      o[0] = r[0]; o[1] = r[1]; o[2] = r[2]; o[3] = r[3]; o[4] = r[4]; o[5] = r[5];
    } else {
      // only reachable if fewer than 100 detections survive globally
      o[0] = 0.f; o[1] = 0.f; o[2] = 0.f; o[3] = 0.f; o[4] = NEGINF; o[5] = 0.f;
    }
  }
}

extern "C" void kernel_launch(void* const* d_in, const int* in_sizes, int n_in,
                              void* d_out, int out_size, void* d_ws, size_t ws_size,
                              hipStream_t stream) {
  const float* boxes  = (const float*)d_in[0];   // [2048, 324]
  const float* scores = (const float*)d_in[1];   // [2048, 81]
  float* rec = (float*)d_ws;                     // 192000 bytes used
  float* out = (float*)d_out;                    // [100, 6]

  nms_per_class_kernel<<<80, 256, 0, stream>>>(boxes, scores, rec);
  topk_kernel<<<1, 1024, 0, stream>>>(rec, out);
}

// Round 2
// 111.183 us; speedup vs baseline: 2.4215x; 2.4215x over previous
//
#include <hip/hip_runtime.h>
#include <stdint.h>

// Detection post-processor: per-class score threshold + stable sort + greedy
// NMS + global top-100.  N=2048 proposals, C=81 classes (class 0 dropped).
// Inputs:  d_in[0] = boxes  [2048, 324] f32, d_in[1] = scores [2048, 81] f32
// Output:  d_out = [100, 6] f32 (x1,y1,x2,y2,score,label)
// Workspace: rec[80*100*6] f32 = 192000 B of d_ws (fully rewritten each call).

#define NPROP   2048
#define NCLS    81
#define SCORE_T 0.05f
#define NMS_T   0.5f
#define PERCLS  100
#define NREC    (80 * PERCLS)   // 8000
#define NEGINF  -1.0e9f
#define NBIN    4096
#define SELCAP  4096

typedef unsigned long long u64;
typedef unsigned int u32;

// Order-preserving float->uint mapping (ascending floats -> ascending uints).
__device__ __forceinline__ u32 fflip(float f) {
  u32 u = __float_as_uint(f);
  return (u & 0x80000000u) ? ~u : (u | 0x80000000u);
}
__device__ __forceinline__ float funflip(u32 u) {
  u32 v = (u & 0x80000000u) ? (u ^ 0x80000000u) : ~u;
  return __uint_as_float(v);
}

// Descending wave-synchronous bitonic sort of keys[0..P) by wave 0 (64 lanes).
// P must be a power of two. Pairs within a step are disjoint; wave64 lockstep
// + wave_barrier() gives step ordering without __syncthreads.
__device__ __forceinline__ void wave_bitonic_desc(u64* keys, int P, int lane) {
  for (int k = 2; k <= P; k <<= 1) {
    for (int j = k >> 1; j > 0; j >>= 1) {
      for (int i = lane; i < P; i += 64) {
        int ixj = i ^ j;
        if (ixj > i) {
          u64 a = keys[i], b = keys[ixj];
          if (((i & k) == 0) ? (a < b) : (a > b)) { keys[i] = b; keys[ixj] = a; }
        }
      }
      __builtin_amdgcn_wave_barrier();
    }
  }
}

// One block per foreground class: compact candidates, sort (score desc, idx
// asc) == reference's stable argsort(-s_masked), greedy NMS, emit top-100 kept.
__global__ __launch_bounds__(256) void nms_per_class_kernel(
    const float* __restrict__ boxes, const float* __restrict__ scores,
    float* __restrict__ rec) {
  __shared__ u64 keys[NPROP];          // 16 KB
  __shared__ float bx[NPROP][4];       // 32 KB
  __shared__ int keepArr[NPROP];       //  8 KB
  __shared__ int mcount;
  __shared__ int kkShared;
  volatile int* keep = keepArr;
  const int tid = threadIdx.x;
  const int lane = tid;                // valid when tid < 64
  const int c = blockIdx.x + 1;        // class 1..80

  if (tid == 0) mcount = 0;
  __syncthreads();

  // Compact candidates (slot order irrelevant; the sort below is total since
  // keys embed ~idx and are unique -> deterministic result).
  for (int i = tid; i < NPROP; i += 256) {
    float s = scores[i * NCLS + c];
    if (s > SCORE_T) {
      int slot = atomicAdd(&mcount, 1);
      keys[slot] = ((u64)fflip(s) << 32) | (u32)(~(u32)i);
    }
  }
  __syncthreads();
  const int M = mcount;
  int P = 64; while (P < M) P <<= 1;   // pad to pow2 (<= 2048)

  for (int i = M + tid; i < P; i += 256) keys[i] = 0ULL;  // sinks to the end
  __syncthreads();

  if (tid < 64) wave_bitonic_desc(keys, P, lane);
  __syncthreads();

  // Gather + clip candidate boxes (reference clip: x in [0,1332], y in [0,799]).
  for (int r = tid; r < M; r += 256) {
    u32 pi = ~(u32)(keys[r] & 0xFFFFFFFFull);
    const float* bp = boxes + (size_t)pi * (NCLS * 4) + c * 4;
    bx[r][0] = fminf(fmaxf(bp[0], 0.f), 1332.f);
    bx[r][1] = fminf(fmaxf(bp[1], 0.f), 799.f);
    bx[r][2] = fminf(fmaxf(bp[2], 0.f), 1332.f);
    bx[r][3] = fminf(fmaxf(bp[3], 0.f), 799.f);
    keepArr[r] = 1;
  }
  __syncthreads();

  // Greedy NMS by wave 0 only (wave-sync, no block barriers) with fused
  // emission: when row i survives, it is final (suppression only from smaller
  // i) -> lane 0 writes its record immediately. Stop once 100 kept (a class
  // can contribute at most 100 of the global top-100).
  float* base = rec + (size_t)(c - 1) * PERCLS * 6;
  if (tid < 64) {
    int kk = 0;
    for (int i = 0; i < M && kk < PERCLS; ++i) {
      int ki = keep[i];
      float ax1 = bx[i][0], ay1 = bx[i][1], ax2 = bx[i][2], ay2 = bx[i][3];
      __builtin_amdgcn_wave_barrier();
      if (ki) {
        float aarea = fmaxf(ax2 - ax1, 0.f) * fmaxf(ay2 - ay1, 0.f);
        for (int j = i + 1 + lane; j < M; j += 64) {
          if (keep[j]) {
            float ix1 = fmaxf(ax1, bx[j][0]);
            float iy1 = fmaxf(ay1, bx[j][1]);
            float ix2 = fminf(ax2, bx[j][2]);
            float iy2 = fminf(ay2, bx[j][3]);
            float inter = fmaxf(ix2 - ix1, 0.f) * fmaxf(iy2 - iy1, 0.f);
            float barea = fmaxf(bx[j][2] - bx[j][0], 0.f) *
                          fmaxf(bx[j][3] - bx[j][1], 0.f);
            float iou = inter / (aarea + barea - inter + 1e-9f);
            if (iou > NMS_T) keep[j] = 0;
          }
        }
        if (lane == 0) {
          float* o = base + kk * 6;
          o[0] = ax1; o[1] = ay1; o[2] = ax2; o[3] = ay2;
          o[4] = funflip((u32)(keys[i] >> 32)); o[5] = (float)c;
        }
        ++kk;
      }
      __builtin_amdgcn_wave_barrier();
    }
    if (lane == 0) kkShared = kk;
  }
  __syncthreads();

  // Pad the rest (topk reads every slot's score; boxes only read for selected
  // entries, which are real whenever >=100 detections survive globally).
  for (int slot = kkShared + tid; slot < PERCLS; slot += 256) {
    float* o = base + slot * 6;
    o[0] = 0.f; o[1] = 0.f; o[2] = 0.f; o[3] = 0.f; o[4] = NEGINF; o[5] = 0.f;
  }
}

// Global top-100 via monotone bucket histogram + tiny sort.
// Bucket = bits [26:15] of fflip(score). For real scores in (0.05, 1],
// bits [31:27] of fflip are constant (0b10111), so the bucket is monotone in
// the full key; anything else (the NEGINF pads) is forced to bucket 0, which
// is consistent since pad keys are smaller than every real key.
__global__ __launch_bounds__(256) void topk_kernel(
    const float* __restrict__ rec, float* __restrict__ out) {
  __shared__ u32 hist[NBIN];           // 16 KB
  __shared__ u64 sel[SELCAP];          // 32 KB
  __shared__ int selCount;
  __shared__ volatile int sC;
  __shared__ volatile u32 sNeed;
  __shared__ volatile int sB;
  const int tid = threadIdx.x;

  for (int b = tid; b < NBIN; b += 256) hist[b] = 0;
  if (tid == 0) selCount = 0;
  __syncthreads();

  for (int e = tid; e < NREC; e += 256) {
    u32 k32 = fflip(rec[(size_t)e * 6 + 4]);
    int bucket = ((k32 >> 27) == 0x17u) ? (int)((k32 >> 15) & 0xFFFu) : 0;
    atomicAdd(&hist[bucket], 1);
  }
  __syncthreads();

  // Wave 0: find bucket B containing the 100th-largest score.
  if (tid < 64) {
    const int lane = tid;
    // coarse: lane covers bins [lane*64, lane*64+64)
    u32 p = 0;
    for (int t = 0; t < 64; ++t) p += hist[lane * 64 + t];
    u32 S = p;                               // inclusive suffix over chunks
    for (int off = 1; off < 64; off <<= 1) {
      u32 v = __shfl_down(S, off, 64);
      if (lane + off < 64) S += v;
    }
    u32 Sn = __shfl_down(S, 1, 64);
    if (lane == 63) Sn = 0;
    if (S >= 100u && Sn < 100u) { sC = lane; sNeed = 100u - Sn; }
    __builtin_amdgcn_wave_barrier();
    const int C = sC;
    const u32 need2 = sNeed;
    // fine: within chunk C
    u32 T = hist[C * 64 + lane];             // inclusive suffix over bins
    for (int off = 1; off < 64; off <<= 1) {
      u32 v = __shfl_down(T, off, 64);
      if (lane + off < 64) T += v;
    }
    u32 Tn = __shfl_down(T, 1, 64);
    if (lane == 63) Tn = 0;
    if (T >= need2 && Tn < need2) sB = C * 64 + lane;
    __builtin_amdgcn_wave_barrier();
  }
  __syncthreads();
  const int B = sB;

  // Compact every entry with bucket >= B (count in [100, ~B-bin width + 99]).
  for (int e = tid; e < NREC; e += 256) {
    u32 k32 = fflip(rec[(size_t)e * 6 + 4]);
    int bucket = ((k32 >> 27) == 0x17u) ? (int)((k32 >> 15) & 0xFFFu) : 0;
    if (bucket >= B) {
      int slot = atomicAdd(&selCount, 1);
      if (slot < SELCAP) sel[slot] = ((u64)k32 << 32) | (u32)(~(u32)e);
    }
  }
  __syncthreads();
  const int CB = min(selCount, SELCAP);
  int P = 128; while (P < CB) P <<= 1;       // <= 4096
  for (int i = CB + tid; i < P; i += 256) sel[i] = 0ULL;
  __syncthreads();

  if (tid < 64) wave_bitonic_desc(sel, P, tid);
  __syncthreads();

  if (tid < PERCLS) {
    u64 key = sel[tid];
    u32 e = ~(u32)(key & 0xFFFFFFFFull);
    float* o = out + tid * 6;
    if (key != 0ULL && e < NREC) {
      const float* r = rec + (size_t)e * 6;
      o[0] = r[0]; o[1] = r[1]; o[2] = r[2]; o[3] = r[3]; o[4] = r[4]; o[5] = r[5];
    } else {
      // only reachable if fewer than 100 detections survive globally
      o[0] = 0.f; o[1] = 0.f; o[2] = 0.f; o[3] = 0.f; o[4] = NEGINF; o[5] = 0.f;
    }
  }
}

extern "C" void kernel_launch(void* const* d_in, const int* in_sizes, int n_in,
                              void* d_out, int out_size, void* d_ws, size_t ws_size,
                              hipStream_t stream) {
  const float* boxes  = (const float*)d_in[0];   // [2048, 324]
  const float* scores = (const float*)d_in[1];   // [2048, 81]
  float* rec = (float*)d_ws;                     // 192000 bytes used
  float* out = (float*)d_out;                    // [100, 6]

  nms_per_class_kernel<<<80, 256, 0, stream>>>(boxes, scores, rec);
  topk_kernel<<<1, 256, 0, stream>>>(rec, out);
}

// Round 3
// 70.895 us; speedup vs baseline: 3.7976x; 1.5683x over previous
//
#include <hip/hip_runtime.h>
#include <stdint.h>

// Detection post-processor: per-class score threshold + stable sort + greedy
// NMS + global top-100.  N=2048 proposals, C=81 classes (class 0 dropped).
// Inputs:  d_in[0] = boxes  [2048, 324] f32, d_in[1] = scores [2048, 81] f32
// Output:  d_out = [100, 6] f32 (x1,y1,x2,y2,score,label)
// Workspace (192000 B, fully rewritten each call):
//   sarr[8000] f32   : per-(class,rank) score (NEGINF pad)
//   rec5[8000][5] f32: x1,y1,x2,y2,label

#define NPROP   2048
#define NCLS    81
#define SCORE_T 0.05f
#define NMS_T   0.5f
#define PERCLS  100
#define NREC    (80 * PERCLS)   // 8000
#define NEGINF  -1.0e9f
#define NBIN    4096
#define SELCAP  4096

typedef unsigned long long u64;
typedef unsigned int u32;

// Order-preserving float->uint mapping (ascending floats -> ascending uints).
__device__ __forceinline__ u32 fflip(float f) {
  u32 u = __float_as_uint(f);
  return (u & 0x80000000u) ? ~u : (u | 0x80000000u);
}
__device__ __forceinline__ float funflip(u32 u) {
  u32 v = (u & 0x80000000u) ? (u ^ 0x80000000u) : ~u;
  return __uint_as_float(v);
}
__device__ __forceinline__ float rdlane_f(float v, int i) {
  return __uint_as_float(__builtin_amdgcn_readlane(__float_as_uint(v), i));
}

// Descending wave-synchronous bitonic sort of keys[0..P) by one wave.
__device__ __forceinline__ void wave_bitonic_desc(u64* keys, int P, int lane) {
  for (int k = 2; k <= P; k <<= 1) {
    for (int j = k >> 1; j > 0; j >>= 1) {
      for (int i = lane; i < P; i += 64) {
        int ixj = i ^ j;
        if (ixj > i) {
          u64 a = keys[i], b = keys[ixj];
          if (((i & k) == 0) ? (a < b) : (a > b)) { keys[i] = b; keys[ixj] = a; }
        }
      }
      __builtin_amdgcn_wave_barrier();
    }
  }
}

// One block per foreground class: compact candidates, sort (score desc, idx
// asc) == reference's stable argsort(-s_masked), register-resident greedy NMS.
__global__ __launch_bounds__(256) void nms_per_class_kernel(
    const float* __restrict__ boxes, const float* __restrict__ scores,
    float* __restrict__ rec5, float* __restrict__ sarr) {
  __shared__ u64 keys[NPROP];          // 16 KB
  __shared__ float4 keptBx[PERCLS];    // 1.6 KB kept-box list for cross-chunk
  __shared__ int mcount;
  __shared__ int kkOut;
  const int tid = threadIdx.x;
  const int lane = tid;                // valid when tid < 64
  const int c = blockIdx.x + 1;        // class 1..80

  if (tid == 0) mcount = 0;
  __syncthreads();

  // Compact candidates (slot order irrelevant; sort is total: unique keys).
  for (int i = tid; i < NPROP; i += 256) {
    float s = scores[i * NCLS + c];
    if (s > SCORE_T) {
      int slot = atomicAdd(&mcount, 1);
      keys[slot] = ((u64)fflip(s) << 32) | (u32)(~(u32)i);
    }
  }
  __syncthreads();
  const int M = mcount;
  int P = 64; while (P < M) P <<= 1;   // pad to pow2 (<= 2048)
  for (int i = M + tid; i < P; i += 256) keys[i] = 0ULL;  // sinks to the end
  __syncthreads();

  float* base5 = rec5 + (size_t)(c - 1) * PERCLS * 5;
  float* sbase = sarr + (c - 1) * PERCLS;

  if (tid < 64) {
    wave_bitonic_desc(keys, P, lane);
    __builtin_amdgcn_wave_barrier();

    // Register-resident greedy NMS over chunks of 64 sorted candidates.
    int kk = 0;
    const int NC = (M + 63) >> 6;
    for (int q = 0; q < NC && kk < PERCLS; ++q) {
      const int cbase = q << 6;
      const int cnt = min(64, M - cbase);
      u64 mykey = 0ULL;
      float4 b = make_float4(0.f, 0.f, 0.f, 0.f);
      int alive = 0;
      if (lane < cnt) {
        mykey = keys[cbase + lane];
        u32 pi = ~(u32)(mykey & 0xFFFFFFFFull);
        // row stride 1296 B and c*16 B offset are both 16B-aligned -> float4.
        const float4 r = *(const float4*)(boxes + (size_t)pi * (NCLS * 4) + c * 4);
        b.x = fminf(fmaxf(r.x, 0.f), 1332.f);
        b.y = fminf(fmaxf(r.y, 0.f), 799.f);
        b.z = fminf(fmaxf(r.z, 0.f), 1332.f);
        b.w = fminf(fmaxf(r.w, 0.f), 799.f);
        alive = 1;
      }
      const float barea = fmaxf(b.z - b.x, 0.f) * fmaxf(b.w - b.y, 0.f);

      // Cross-chunk: suppress against all already-kept boxes (pipelined LDS).
      for (int t = 0; t < kk; ++t) {
        float4 kb = keptBx[t];
        float ka = fmaxf(kb.z - kb.x, 0.f) * fmaxf(kb.w - kb.y, 0.f);
        float ix1 = fmaxf(kb.x, b.x), iy1 = fmaxf(kb.y, b.y);
        float ix2 = fminf(kb.z, b.z), iy2 = fminf(kb.w, b.w);
        float inter = fmaxf(ix2 - ix1, 0.f) * fmaxf(iy2 - iy1, 0.f);
        float iou = inter / (ka + barea - inter + 1e-9f);
        if (alive && iou > NMS_T) alive = 0;
      }

      // Intra-chunk serial greedy via readlane broadcasts (no LDS round-trips).
      for (int i = 0; i < cnt; ++i) {
        int ai = __builtin_amdgcn_readlane(alive, i);
        if (ai) {
          float ax1 = rdlane_f(b.x, i), ay1 = rdlane_f(b.y, i);
          float ax2 = rdlane_f(b.z, i), ay2 = rdlane_f(b.w, i);
          float aarea = fmaxf(ax2 - ax1, 0.f) * fmaxf(ay2 - ay1, 0.f);
          if (lane > i && alive) {
            float ix1 = fmaxf(ax1, b.x), iy1 = fmaxf(ay1, b.y);
            float ix2 = fminf(ax2, b.z), iy2 = fminf(ay2, b.w);
            float inter = fmaxf(ix2 - ix1, 0.f) * fmaxf(iy2 - iy1, 0.f);
            float iou = inter / (aarea + barea - inter + 1e-9f);
            if (iou > NMS_T) alive = 0;
          }
          if (lane == i) {
            float* o = base5 + kk * 5;
            o[0] = b.x; o[1] = b.y; o[2] = b.z; o[3] = b.w; o[4] = (float)c;
            sbase[kk] = funflip((u32)(mykey >> 32));
            keptBx[kk] = b;
          }
          ++kk;
          if (kk >= PERCLS) break;
        }
      }
      __builtin_amdgcn_wave_barrier();
    }
    if (lane == 0) kkOut = kk;
  }
  __syncthreads();

  // Pad remaining slots. (Selected entries are real whenever >=100 detections
  // survive globally, which holds for this workload.)
  for (int slot = kkOut + tid; slot < PERCLS; slot += 256) {
    sbase[slot] = NEGINF;
    float* o = base5 + slot * 5;
    o[0] = 0.f; o[1] = 0.f; o[2] = 0.f; o[3] = 0.f; o[4] = 0.f;
  }
}

// Global top-100 via monotone bucket histogram + tiny sort.
// Bucket = bits [26:15] of fflip(score): for real scores in (0.05, 1] the top
// 5 bits of fflip are constant 0b10111, so bucket order == score order; pads
// (NEGINF) land in bucket 0, consistent since their keys are smaller.
__global__ __launch_bounds__(1024) void topk_kernel(
    const float* __restrict__ rec5, const float* __restrict__ sarr,
    float* __restrict__ out) {
  __shared__ u32 hist[NBIN];           // 16 KB
  __shared__ u64 sel[SELCAP];          // 32 KB
  __shared__ int selCount;
  __shared__ volatile int sC;
  __shared__ volatile u32 sNeed;
  __shared__ volatile int sB;
  const int tid = threadIdx.x;

  for (int b = tid; b < NBIN; b += 1024) hist[b] = 0;
  if (tid == 0) selCount = 0;
  __syncthreads();

  for (int e = tid; e < NREC; e += 1024) {
    u32 k32 = fflip(sarr[e]);
    int bucket = ((k32 >> 27) == 0x17u) ? (int)((k32 >> 15) & 0xFFFu) : 0;
    atomicAdd(&hist[bucket], 1);
  }
  __syncthreads();

  // Wave 0: find bucket B containing the 100th-largest score.
  if (tid < 64) {
    const int lane = tid;
    u32 p = 0;
    for (int t = 0; t < 64; ++t) p += hist[lane * 64 + t];
    u32 S = p;                               // inclusive suffix over chunks
    for (int off = 1; off < 64; off <<= 1) {
      u32 v = __shfl_down(S, off, 64);
      if (lane + off < 64) S += v;
    }
    u32 Sn = __shfl_down(S, 1, 64);
    if (lane == 63) Sn = 0;
    if (S >= 100u && Sn < 100u) { sC = lane; sNeed = 100u - Sn; }
    __builtin_amdgcn_wave_barrier();
    const int C = sC;
    const u32 need2 = sNeed;
    u32 T = hist[C * 64 + lane];             // inclusive suffix over bins
    for (int off = 1; off < 64; off <<= 1) {
      u32 v = __shfl_down(T, off, 64);
      if (lane + off < 64) T += v;
    }
    u32 Tn = __shfl_down(T, 1, 64);
    if (lane == 63) Tn = 0;
    if (T >= need2 && Tn < need2) sB = C * 64 + lane;
    __builtin_amdgcn_wave_barrier();
  }
  __syncthreads();
  const int B = sB;

  // Compact every entry with bucket >= B (typically ~100-300 entries).
  for (int e = tid; e < NREC; e += 1024) {
    u32 k32 = fflip(sarr[e]);
    int bucket = ((k32 >> 27) == 0x17u) ? (int)((k32 >> 15) & 0xFFFu) : 0;
    if (bucket >= B) {
      int slot = atomicAdd(&selCount, 1);
      if (slot < SELCAP) sel[slot] = ((u64)k32 << 32) | (u32)(~(u32)e);
    }
  }
  __syncthreads();
  const int CB = min(selCount, SELCAP);
  int P = 128; while (P < CB) P <<= 1;       // <= 4096
  for (int i = CB + tid; i < P; i += 1024) sel[i] = 0ULL;
  __syncthreads();

  if (tid < 64) wave_bitonic_desc(sel, P, tid);
  __syncthreads();

  if (tid < PERCLS) {
    u64 key = sel[tid];
    u32 e = ~(u32)(key & 0xFFFFFFFFull);
    float* o = out + tid * 6;
    if (key != 0ULL && e < NREC) {
      const float* r = rec5 + (size_t)e * 5;
      o[0] = r[0]; o[1] = r[1]; o[2] = r[2]; o[3] = r[3];
      o[4] = funflip((u32)(key >> 32)); o[5] = r[4];
    } else {
      // only reachable if fewer than 100 detections survive globally
      o[0] = 0.f; o[1] = 0.f; o[2] = 0.f; o[3] = 0.f; o[4] = NEGINF; o[5] = 0.f;
    }
  }
}

extern "C" void kernel_launch(void* const* d_in, const int* in_sizes, int n_in,
                              void* d_out, int out_size, void* d_ws, size_t ws_size,
                              hipStream_t stream) {
  const float* boxes  = (const float*)d_in[0];   // [2048, 324]
  const float* scores = (const float*)d_in[1];   // [2048, 81]
  float* sarr = (float*)d_ws;                    // [8000]
  float* rec5 = sarr + NREC;                     // [8000][5]  (192000 B total)
  float* out  = (float*)d_out;                   // [100, 6]

  nms_per_class_kernel<<<80, 256, 0, stream>>>(boxes, scores, rec5, sarr);
  topk_kernel<<<1, 1024, 0, stream>>>(rec5, sarr, out);
}

// Round 4
// 58.260 us; speedup vs baseline: 4.6213x; 1.2169x over previous
//
#include <hip/hip_runtime.h>
#include <stdint.h>

// Detection post-processor, single fused kernel:
// per-class score threshold + stable sort + greedy NMS + global top-100.
// N=2048 proposals, C=81 classes (class 0 dropped).
// Inputs:  d_in[0] = boxes  [2048, 324] f32, d_in[1] = scores [2048, 81] f32
// Output:  d_out = [100, 6] f32 (x1,y1,x2,y2,score,label)
// Workspace layout (<= 192000 B, fully rewritten each call):
//   [0]      u32 counter   (zeroed each call by hipMemsetAsync graph node)
//   [64]     sarr[8000]    f32 per-(class,rank) score (NEGINF pad)
//   [32064]  rec4[8000]    float4 clipped boxes  (label derived from index)

#define NPROP   2048
#define NCLS    81
#define SCORE_T 0.05f
#define NMS_T   0.5f
#define PERCLS  100
#define NREC    (80 * PERCLS)   // 8000
#define NEGINF  -1.0e9f
#define NBIN    4096
#define SELCAP  4096
#define MCAP    256             // fast-path candidate cap per class

typedef unsigned long long u64;
typedef unsigned int u32;

// Order-preserving float->uint mapping (ascending floats -> ascending uints).
__device__ __forceinline__ u32 fflip(float f) {
  u32 u = __float_as_uint(f);
  return (u & 0x80000000u) ? ~u : (u | 0x80000000u);
}
__device__ __forceinline__ float funflip(u32 u) {
  u32 v = (u & 0x80000000u) ? (u ^ 0x80000000u) : ~u;
  return __uint_as_float(v);
}
__device__ __forceinline__ float rdlane_f(float v, int i) {
  return __uint_as_float(__builtin_amdgcn_readlane(__float_as_uint(v), i));
}

// Key layout (64b), compare order == (score desc, proposal idx asc), matching
// the reference's stable argsort(-s_masked). Slot bits sit BELOW the unique
// (2047-idx) bits so they never affect ordering between distinct candidates.
//   [63:32] fflip(score)   [31:11+11=22..11] (2047-idx)  [10:0] compact slot

__global__ __launch_bounds__(256) void postproc_kernel(
    const float* __restrict__ boxes, const float* __restrict__ scores,
    float* __restrict__ sarr, float4* __restrict__ rec4,
    u32* __restrict__ gcnt, float* __restrict__ out) {
  __shared__ __align__(16) char arena[50176];
  u64*    keysIn   = (u64*)arena;                   // [2048]  16384 B
  u64*    sortedA  = (u64*)(arena + 16384);         // [256]    2048 B
  float4* bxArr    = (float4*)(arena + 18432);      // [256]    4096 B
  float4* keptBx   = (float4*)(arena + 22528);      // [100]    1600 B
  float*  keptArea = (float*)(arena + 24128);       // [100]     400 B
  // --- topk overlay (only used by the last block, after its NMS is done) ---
  u32*    hist     = (u32*)arena;                   // [4096]  16384 B
  u64*    sel      = (u64*)(arena + 16384);         // [4096]  32768 B
  u64*    selSorted= (u64*)(arena + 49152);         // [128]    1024 B

  __shared__ int mcount, kkOut, lastOld, selCount;
  __shared__ volatile int sC, sB;
  __shared__ volatile u32 sNeed;

  const int tid = threadIdx.x;
  const int c = blockIdx.x + 1;                     // class 1..80

  if (tid == 0) mcount = 0;
  __syncthreads();

  // ---- Phase 1: score scan + candidate compact + box gather/clip ----
  for (int i = tid; i < NPROP; i += 256) {
    float s = scores[i * NCLS + c];
    if (s > SCORE_T) {
      int slot = atomicAdd(&mcount, 1);
      keysIn[slot] = ((u64)fflip(s) << 32) | ((u64)(2047 - i) << 11) |
                     (u64)(slot & 0x7FF);
      if (slot < MCAP) {
        // row stride 1296 B and c*16 B offset are 16B-aligned -> float4.
        const float4 r = *(const float4*)(boxes + (size_t)i * (NCLS * 4) + c * 4);
        float4 b;
        b.x = fminf(fmaxf(r.x, 0.f), 1332.f);
        b.y = fminf(fmaxf(r.y, 0.f), 799.f);
        b.z = fminf(fmaxf(r.z, 0.f), 1332.f);
        b.w = fminf(fmaxf(r.w, 0.f), 799.f);
        bxArr[slot] = b;
      }
    }
  }
  __syncthreads();
  const int M = mcount;
  const bool fastbx = (M <= MCAP);

  // ---- Phase 2: sort candidates (score desc, idx asc) ----
  if (fastbx) {
    // Rank sort: one barrier, broadcast LDS reads, keys unique -> bijection.
    if (tid < M) {
      u64 kr = keysIn[tid];
      int rk = 0;
      for (int j = 0; j < M; ++j) rk += (keysIn[j] > kr) ? 1 : 0;
      sortedA[rk] = kr;
    }
    __syncthreads();
  } else {
    // Fallback (data-safety only): block-wide bitonic, in place.
    int P = 256; while (P < M) P <<= 1;
    for (int i = M + tid; i < P; i += 256) keysIn[i] = 0ULL;
    __syncthreads();
    for (int k = 2; k <= P; k <<= 1) {
      for (int j = k >> 1; j > 0; j >>= 1) {
        for (int i = tid; i < P; i += 256) {
          int ixj = i ^ j;
          if (ixj > i) {
            u64 a = keysIn[i], b = keysIn[ixj];
            if (((i & k) == 0) ? (a < b) : (a > b)) { keysIn[i] = b; keysIn[ixj] = a; }
          }
        }
        __syncthreads();
      }
    }
  }
  const u64* SK = fastbx ? sortedA : keysIn;

  float* sbase = sarr + (c - 1) * PERCLS;
  float4* recB = rec4 + (size_t)(c - 1) * PERCLS;

  // ---- Phase 3: greedy NMS (wave 0, register-resident, ballot-driven) ----
  if (tid < 64) {
    const int lane = tid;
    int kk = 0;
    const int NC = (M + 63) >> 6;
    for (int q = 0; q < NC && kk < PERCLS; ++q) {
      const int cbase = q << 6;
      const int cnt = min(64, M - cbase);
      u64 mykey = 0ULL;
      float4 b = make_float4(0.f, 0.f, 0.f, 0.f);
      int alive = 0;
      if (lane < cnt) {
        mykey = SK[cbase + lane];
        if (fastbx) {
          b = bxArr[(int)(mykey & 0x7FF)];
        } else {
          u32 pi = 2047u - (u32)((mykey >> 11) & 0x7FF);
          const float4 r = *(const float4*)(boxes + (size_t)pi * (NCLS * 4) + c * 4);
          b.x = fminf(fmaxf(r.x, 0.f), 1332.f);
          b.y = fminf(fmaxf(r.y, 0.f), 799.f);
          b.z = fminf(fmaxf(r.z, 0.f), 1332.f);
          b.w = fminf(fmaxf(r.w, 0.f), 799.f);
        }
        alive = 1;
      }
      const float barea = fmaxf(b.z - b.x, 0.f) * fmaxf(b.w - b.y, 0.f);

      // Cross-chunk: suppress against already-kept boxes (pipelined LDS).
      for (int t = 0; t < kk; ++t) {
        float4 kb = keptBx[t];
        float ka = keptArea[t];
        float ix1 = fmaxf(kb.x, b.x), iy1 = fmaxf(kb.y, b.y);
        float ix2 = fminf(kb.z, b.z), iy2 = fminf(kb.w, b.w);
        float inter = fmaxf(ix2 - ix1, 0.f) * fmaxf(iy2 - iy1, 0.f);
        float iou = inter / (ka + barea - inter + 1e-9f);
        if (iou > NMS_T) alive = 0;
      }

      // Intra-chunk: iterate only alive candidates in score order.
      u64 work = __ballot(alive != 0);
      while (work) {
        int i = __builtin_ctzll(work);
        float ax1 = rdlane_f(b.x, i), ay1 = rdlane_f(b.y, i);
        float ax2 = rdlane_f(b.z, i), ay2 = rdlane_f(b.w, i);
        float aarea = rdlane_f(barea, i);
        bool sup = false;
        if (alive && lane > i) {
          float ix1 = fmaxf(ax1, b.x), iy1 = fmaxf(ay1, b.y);
          float ix2 = fminf(ax2, b.z), iy2 = fminf(ay2, b.w);
          float inter = fmaxf(ix2 - ix1, 0.f) * fmaxf(iy2 - iy1, 0.f);
          float iou = inter / (aarea + barea - inter + 1e-9f);
          sup = iou > NMS_T;
        }
        if (sup) alive = 0;
        u64 supb = __ballot(sup);
        if (lane == i) {
          recB[kk] = b;
          sbase[kk] = funflip((u32)(mykey >> 32));
          keptBx[kk] = b;
          keptArea[kk] = barea;
        }
        ++kk;
        work &= ~supb;
        work &= (work - 1ULL);            // clear bit i (still lowest set)
        if (kk >= PERCLS) break;
        __builtin_amdgcn_wave_barrier();
      }
    }
    if (lane == 0) kkOut = kk;
  }
  __syncthreads();

  // Pad remaining slots. (Selected top-100 entries are real whenever >=100
  // detections survive globally, which holds for this workload.)
  for (int slot = kkOut + tid; slot < PERCLS; slot += 256) {
    sbase[slot] = NEGINF;
    recB[slot] = make_float4(0.f, 0.f, 0.f, 0.f);
  }

  // ---- Phase 4: last block to finish runs the global top-100 ----
  __threadfence();          // release this block's sarr/rec4 stores
  __syncthreads();
  if (tid == 0) lastOld = (int)atomicAdd(gcnt, 1u);   // device-scope
  __syncthreads();
  if (lastOld != 79) return;

  __threadfence();          // acquire: see all other blocks' stores
  for (int b = tid; b < NBIN; b += 256) hist[b] = 0;
  if (tid == 0) selCount = 0;
  __syncthreads();

  // Bucket = bits [26:15] of fflip(score): real scores in (0.05,1] share the
  // top 5 bits (0b10111) so bucket order == score order; NEGINF pads land in
  // bucket 0, consistent since their keys are smaller than every real key.
  const float4* s4p = (const float4*)sarr;
  for (int e4 = tid; e4 < NREC / 4; e4 += 256) {
    float4 s4 = s4p[e4];
    #pragma unroll
    for (int t = 0; t < 4; ++t) {
      float sv = (t == 0) ? s4.x : (t == 1) ? s4.y : (t == 2) ? s4.z : s4.w;
      u32 k32 = fflip(sv);
      int bucket = ((k32 >> 27) == 0x17u) ? (int)((k32 >> 15) & 0xFFFu) : 0;
      atomicAdd(&hist[bucket], 1);
    }
  }
  __syncthreads();

  // Wave 0: find bucket B containing the 100th-largest score.
  if (tid < 64) {
    const int lane = tid;
    u32 p = 0;
    for (int t = 0; t < 64; ++t) p += hist[lane * 64 + t];
    u32 S = p;                               // inclusive suffix over chunks
    for (int off = 1; off < 64; off <<= 1) {
      u32 v = __shfl_down(S, off, 64);
      if (lane + off < 64) S += v;
    }
    u32 Sn = __shfl_down(S, 1, 64);
    if (lane == 63) Sn = 0;
    if (S >= 100u && Sn < 100u) { sC = lane; sNeed = 100u - Sn; }
    __builtin_amdgcn_wave_barrier();
    const int C = sC;
    const u32 need2 = sNeed;
    u32 T = hist[C * 64 + lane];             // inclusive suffix over bins
    for (int off = 1; off < 64; off <<= 1) {
      u32 v = __shfl_down(T, off, 64);
      if (lane + off < 64) T += v;
    }
    u32 Tn = __shfl_down(T, 1, 64);
    if (lane == 63) Tn = 0;
    if (T >= need2 && Tn < need2) sB = C * 64 + lane;
    __builtin_amdgcn_wave_barrier();
  }
  __syncthreads();
  const int B = sB;

  // Compact entries with bucket >= B (>=100 by construction, typically ~100s).
  for (int e4 = tid; e4 < NREC / 4; e4 += 256) {
    float4 s4 = s4p[e4];
    #pragma unroll
    for (int t = 0; t < 4; ++t) {
      float sv = (t == 0) ? s4.x : (t == 1) ? s4.y : (t == 2) ? s4.z : s4.w;
      u32 k32 = fflip(sv);
      int bucket = ((k32 >> 27) == 0x17u) ? (int)((k32 >> 15) & 0xFFFu) : 0;
      if (bucket >= B) {
        int slot = atomicAdd(&selCount, 1);
        int e = e4 * 4 + t;
        if (slot < SELCAP) sel[slot] = ((u64)k32 << 32) | (u32)(~(u32)e);
      }
    }
  }
  __syncthreads();
  const int CB = min(selCount, SELCAP);

  // Rank-select the top 100 (CB >= 100 guaranteed; keys unique via ~e bits;
  // tie order == lowest flat index first, matching lax.top_k).
  for (int r = tid; r < CB; r += 256) {
    u64 kr = sel[r];
    int rk = 0;
    for (int j = 0; j < CB; ++j) rk += (sel[j] > kr) ? 1 : 0;
    if (rk < PERCLS) selSorted[rk] = kr;
  }
  __syncthreads();

  if (tid < PERCLS) {
    u64 key = selSorted[tid];
    u32 e = ~(u32)(key & 0xFFFFFFFFull);
    float4 r4 = rec4[e];
    float* o = out + tid * 6;
    o[0] = r4.x; o[1] = r4.y; o[2] = r4.z; o[3] = r4.w;
    o[4] = funflip((u32)(key >> 32));
    o[5] = (float)(e / PERCLS + 1);          // class label from entry index
  }
}

extern "C" void kernel_launch(void* const* d_in, const int* in_sizes, int n_in,
                              void* d_out, int out_size, void* d_ws, size_t ws_size,
                              hipStream_t stream) {
  const float* boxes  = (const float*)d_in[0];   // [2048, 324]
  const float* scores = (const float*)d_in[1];   // [2048, 81]
  char* ws = (char*)d_ws;
  u32*    gcnt = (u32*)ws;                       // 4 B counter at offset 0
  float*  sarr = (float*)(ws + 64);              // [8000] f32
  float4* rec4 = (float4*)(ws + 64 + 32000);     // [8000] float4 (16B aligned)
  float*  out  = (float*)d_out;                  // [100, 6]

  hipMemsetAsync(gcnt, 0, 4, stream);            // graph-capture-legal node
  postproc_kernel<<<80, 256, 0, stream>>>(boxes, scores, sarr, rec4, gcnt, out);
}